// Round 7
// baseline (558.467 us; speedup 1.0000x reference)
//
#include <hip/hip_runtime.h>

typedef unsigned short u16;
typedef __attribute__((ext_vector_type(8))) short short8;
typedef __attribute__((ext_vector_type(4))) float float4v;

#define MFMA16(a, b, c) __builtin_amdgcn_mfma_f32_16x16x32_bf16((a), (b), (c), 0, 0, 0)

// ---------------- helpers ----------------
__device__ __forceinline__ u16 f2b(float x) {
    union { float f; unsigned u; } v; v.f = x;
    unsigned r = v.u + 0x7FFFu + ((v.u >> 16) & 1u);   // RNE
    return (u16)(r >> 16);
}
__device__ __forceinline__ float b2f(u16 u) {
    union { unsigned u; float f; } v; v.u = ((unsigned)u) << 16; return v.f;
}

// constants
#define NH 16
#define S  2048
#define HD 64
#define H  1024
// scale = 1/sqrt(192) * log2(e)  (exp -> exp2 folded into all score terms)
#define SC 0.10412111829775301f

// ---------------- workspace offsets (bytes) ----------------
#define OFF_REB   0ull
#define OFF_HSB   (OFF_REB  + 1048576ull)
#define OFF_WT    (OFF_HSB  + 8388608ull)
#define OFF_QB    (OFF_WT   + 12582912ull)
#define OFF_KB    (OFF_QB   + 8388608ull)
#define OFF_VT    (OFF_KB   + 8388608ull)
#define OFF_PKB   (OFF_VT   + 8388608ull)
#define OFF_PQB   (OFF_PKB  + 1048576ull)
#define OFF_C2P   (OFF_PQB  + 1048576ull)                // 64 MB [bh][q][512]
#define OFF_P2CT  (OFF_C2P  + 67108864ull)               // 64 MB [bh][p][2048]
#define OFF_CTX   (OFF_P2CT + 67108864ull)
#define OFF_IDX   (OFF_CTX  + 8388608ull)
#define OFF_SP    (OFF_IDX  + 8192ull)                   // split-K partials
#define SP_OHALF  4194304ull                             // floats per half (32*2048*64)
#define SP_LBASE  (OFF_SP + 67108864ull)
#define SP_LHALF  65536ull
#define WS_NEED_SPLIT (SP_LBASE + 524288ull)             // ~248 MB

// ---------------- idx table for rel in [-512, 511] ----------------
// idx(rel<=-512)==0, idx(rel>=506)==511, idx monotone => clamping rel to [-512,511] is EXACT.
__global__ void k_build_idx(short* __restrict__ t) {
    int i = blockIdx.x * 256 + threadIdx.x;
    if (i >= 1024) return;
    int rel = i - 512;
    float fr = (float)rel;
    float abs_pos = (rel < 128 && rel > -128) ? 127.0f : fabsf(fr);
    const float LOGC = 1.3843393262841284f;  // float32(ln(511/128))
    float log_pos = ceilf(logf(abs_pos * (1.0f / 128.0f)) / LOGC * 127.0f) + 128.0f;
    float sgn = (fr > 0.f) ? 1.f : ((fr < 0.f) ? -1.f : 0.f);
    float bf = (abs_pos <= 128.0f) ? fr : log_pos * sgn;
    int idx = (int)bf + 256;
    idx = idx < 0 ? 0 : (idx > 511 ? 511 : idx);
    t[i] = (short)idx;
}

// ---------------- LayerNorm of rel_emb -> bf16 ----------------
__global__ __launch_bounds__(256) void k_ln(const float* __restrict__ re,
                                            const float* __restrict__ g,
                                            const float* __restrict__ be,
                                            u16* __restrict__ out) {
    int row = blockIdx.x;
    const float4* x4 = (const float4*)(re + (size_t)row * H);
    int tid = threadIdx.x;
    float4 vv = x4[tid];
    float s = vv.x + vv.y + vv.z + vv.w;
    float s2 = vv.x * vv.x + vv.y * vv.y + vv.z * vv.z + vv.w * vv.w;
    for (int m = 1; m < 64; m <<= 1) {
        s += __shfl_xor(s, m, 64);
        s2 += __shfl_xor(s2, m, 64);
    }
    __shared__ float as[4], as2[4];
    if ((tid & 63) == 0) { as[tid >> 6] = s; as2[tid >> 6] = s2; }
    __syncthreads();
    s = as[0] + as[1] + as[2] + as[3];
    s2 = as2[0] + as2[1] + as2[2] + as2[3];
    float mu = s * (1.f / 1024.f);
    float var = s2 * (1.f / 1024.f) - mu * mu;
    float rstd = rsqrtf(var + 1e-5f);
    float4 gg = ((const float4*)g)[tid];
    float4 bb = ((const float4*)be)[tid];
    ushort4 r4;
    r4.x = f2b((vv.x - mu) * rstd * gg.x + bb.x);
    r4.y = f2b((vv.y - mu) * rstd * gg.y + bb.y);
    r4.z = f2b((vv.z - mu) * rstd * gg.z + bb.z);
    r4.w = f2b((vv.w - mu) * rstd * gg.w + bb.w);
    ((ushort4*)(out + (size_t)row * H))[tid] = r4;
}

// ---------------- fp32 -> bf16 cast ----------------
__global__ __launch_bounds__(256) void k_cast(const float* __restrict__ x, u16* __restrict__ y) {
    int i = blockIdx.x * 256 + threadIdx.x;
    float4 v = ((const float4*)x)[i];
    ushort4 r;
    r.x = f2b(v.x); r.y = f2b(v.y); r.z = f2b(v.z); r.w = f2b(v.w);
    ((ushort4*)y)[i] = r;
}

// ---------------- 6x weight transpose + cast ----------------
__global__ __launch_bounds__(256) void k_wt6(const float* __restrict__ W0, const float* __restrict__ W1,
                                             const float* __restrict__ W2, const float* __restrict__ W3,
                                             const float* __restrict__ W4, const float* __restrict__ W5,
                                             u16* __restrict__ T0, u16* __restrict__ T1,
                                             u16* __restrict__ T2, u16* __restrict__ T3,
                                             u16* __restrict__ T4, u16* __restrict__ T5) {
    const float* W; u16* WT;
    switch (blockIdx.z) {
        case 0: W = W0; WT = T0; break;
        case 1: W = W1; WT = T1; break;
        case 2: W = W2; WT = T2; break;
        case 3: W = W3; WT = T3; break;
        case 4: W = W4; WT = T4; break;
        default: W = W5; WT = T5; break;
    }
    __shared__ float t[64][65];
    int k0 = blockIdx.x * 64, n0 = blockIdx.y * 64;
    int tid = threadIdx.x;
#pragma unroll
    for (int i = 0; i < 16; i++) {
        int lin = tid + 256 * i;
        int r = lin >> 6, c = lin & 63;
        t[r][c] = W[(size_t)(k0 + r) * H + n0 + c];
    }
    __syncthreads();
#pragma unroll
    for (int i = 0; i < 16; i++) {
        int lin = tid + 256 * i;
        int r = lin >> 6, c = lin & 63;
        WT[(size_t)(n0 + r) * H + k0 + c] = f2b(t[c][r]);
    }
}

// ---------------- 128x128-tile GEMM core ----------------
// MODE 0: bf16 row-major; MODE 1: f32 row-major;
// MODE 2: bf16 VT layout (b*1024+n)*2048 + m ; MODE 3: bf16 head-major ((b*16+h)*2048+m)*64+d
template <int MODE>
__device__ __forceinline__ void gemm2_body(const u16* __restrict__ A,
                                           const u16* __restrict__ Bt,
                                           const float* __restrict__ bias,
                                           void* __restrict__ C, int N, int K) {
    __shared__ __align__(16) u16 As[128 * 32];
    __shared__ __align__(16) u16 Bs[128 * 32];
    int tid = threadIdx.x;
    int lane = tid & 63, w = tid >> 6;
    int ln = lane & 15, quad = lane >> 4;
    int m0 = blockIdx.x * 128, n0 = blockIdx.y * 128;
    int wm = (w >> 1) * 64, wn = (w & 1) * 64;
    float4v acc[4][4];
    float4v zero = {0.f, 0.f, 0.f, 0.f};
#pragma unroll
    for (int mi = 0; mi < 4; mi++)
#pragma unroll
        for (int ni = 0; ni < 4; ni++) acc[mi][ni] = zero;

    int r1 = tid >> 2, o1 = (tid & 3) * 8;
    const u16* ga1 = A + (size_t)(m0 + r1) * K + o1;
    const u16* gb1 = Bt + (size_t)(n0 + r1) * K + o1;
    u16* sa1 = &As[r1 * 32 + o1];
    u16* sb1 = &Bs[r1 * 32 + o1];
    size_t step2 = (size_t)64 * K;

    for (int k0 = 0; k0 < K; k0 += 32) {
        short8 va1 = *(const short8*)(ga1 + k0);
        short8 va2 = *(const short8*)(ga1 + step2 + k0);
        short8 vb1 = *(const short8*)(gb1 + k0);
        short8 vb2 = *(const short8*)(gb1 + step2 + k0);
        __syncthreads();
        *(short8*)sa1 = va1; *(short8*)(sa1 + 2048) = va2;
        *(short8*)sb1 = vb1; *(short8*)(sb1 + 2048) = vb2;
        __syncthreads();
        short8 af[4], bf[4];
#pragma unroll
        for (int mi = 0; mi < 4; mi++)
            af[mi] = *(const short8*)&As[(wm + mi * 16 + ln) * 32 + quad * 8];
#pragma unroll
        for (int ni = 0; ni < 4; ni++)
            bf[ni] = *(const short8*)&Bs[(wn + ni * 16 + ln) * 32 + quad * 8];
#pragma unroll
        for (int mi = 0; mi < 4; mi++)
#pragma unroll
            for (int ni = 0; ni < 4; ni++)
                acc[mi][ni] = MFMA16(af[mi], bf[ni], acc[mi][ni]);
    }

#pragma unroll
    for (int mi = 0; mi < 4; mi++) {
        int row0 = m0 + wm + mi * 16 + quad * 4;
#pragma unroll
        for (int ni = 0; ni < 4; ni++) {
            int col = n0 + wn + ni * 16 + ln;
            float bv = bias[col];
            if (MODE == 0) {
                u16* Cb = (u16*)C;
#pragma unroll
                for (int r = 0; r < 4; r++)
                    Cb[(size_t)(row0 + r) * N + col] = f2b(acc[mi][ni][r] + bv);
            } else if (MODE == 1) {
                float* Cf = (float*)C;
#pragma unroll
                for (int r = 0; r < 4; r++)
                    Cf[(size_t)(row0 + r) * N + col] = acc[mi][ni][r] + bv;
            } else if (MODE == 2) {
                u16* Cb = (u16*)C;
                int bb = row0 >> 11, s = row0 & 2047;
                ushort4 r4;
                r4.x = f2b(acc[mi][ni][0] + bv);
                r4.y = f2b(acc[mi][ni][1] + bv);
                r4.z = f2b(acc[mi][ni][2] + bv);
                r4.w = f2b(acc[mi][ni][3] + bv);
                *(ushort4*)(Cb + ((size_t)(bb * 1024 + col)) * 2048 + s) = r4;
            } else {
                u16* Cb = (u16*)C;
                int bb = row0 >> 11, s = row0 & 2047;
                int h = col >> 6, d = col & 63;
#pragma unroll
                for (int r = 0; r < 4; r++)
                    Cb[((size_t)(bb * 16 + h) * 2048 + s + r) * 64 + d] = f2b(acc[mi][ni][r] + bv);
            }
        }
    }
}

template <int MODE>
__global__ __launch_bounds__(256) void k_gemm2(const u16* __restrict__ A, const u16* __restrict__ Bt,
                                               const float* __restrict__ bias, void* __restrict__ C,
                                               int N, int K) {
    gemm2_body<MODE>(A, Bt, bias, C, N, K);
}

template <int MODE>
__global__ __launch_bounds__(256) void k_gemm2_dual(const u16* __restrict__ A,
                                                    const u16* __restrict__ Bt0, const u16* __restrict__ Bt1,
                                                    const float* __restrict__ b0, const float* __restrict__ b1,
                                                    void* __restrict__ C0, void* __restrict__ C1,
                                                    int N, int K) {
    if (blockIdx.z == 0) gemm2_body<MODE>(A, Bt0, b0, C0, N, K);
    else                 gemm2_body<MODE>(A, Bt1, b1, C1, N, K);
}

// Q/K/V projections in one launch (z: 0=Q head-major, 1=K head-major, 2=V transposed)
__global__ __launch_bounds__(256) void k_qkv(const u16* __restrict__ A,
                                             const u16* __restrict__ W0, const u16* __restrict__ W1,
                                             const u16* __restrict__ W2,
                                             const float* __restrict__ b0, const float* __restrict__ b1,
                                             const float* __restrict__ b2,
                                             u16* __restrict__ Q, u16* __restrict__ K, u16* __restrict__ VT) {
    if (blockIdx.z == 0)      gemm2_body<3>(A, W0, b0, Q, H, H);
    else if (blockIdx.z == 1) gemm2_body<3>(A, W1, b1, K, H, H);
    else                      gemm2_body<2>(A, W2, b2, VT, H, H);
}

// ---------------- both positional score tables, one launch ----------------
__global__ __launch_bounds__(256) void k_pos_both(const u16* __restrict__ Qh, const u16* __restrict__ Kh,
                                                  const u16* __restrict__ pk, const u16* __restrict__ pq,
                                                  u16* __restrict__ c2p, u16* __restrict__ p2cT) {
    __shared__ __align__(16) u16 As[128][72];
    __shared__ __align__(16) u16 Bs[128][72];
    int tid = threadIdx.x;
    int lane = tid & 63, w = tid >> 6;
    int ln = lane & 15, quad = lane >> 4;
    int tr = blockIdx.z & 1, z = blockIdx.z >> 1, h = z & 15;
    int m0 = blockIdx.x * 128, n0 = blockIdx.y * 128;
    const u16* A = (tr ? Kh : Qh) + (size_t)z * S * HD;
    const u16* B = (tr ? pq : pk) + h * 64;
    int sr = tid >> 1, scb = (tid & 1) * 32;
    {
        const u16* ga = A + (size_t)(m0 + sr) * HD + scb;
        const u16* gb = B + (size_t)(n0 + sr) * H + scb;
#pragma unroll
        for (int j = 0; j < 4; j++) {
            *(short8*)&As[sr][scb + j * 8] = *(const short8*)(ga + j * 8);
            *(short8*)&Bs[sr][scb + j * 8] = *(const short8*)(gb + j * 8);
        }
    }
    __syncthreads();
    int wm = (w >> 1) * 64, wn = (w & 1) * 64;
    float4v acc[4][4];
    float4v zero = {0.f, 0.f, 0.f, 0.f};
#pragma unroll
    for (int mi = 0; mi < 4; mi++)
#pragma unroll
        for (int ni = 0; ni < 4; ni++) acc[mi][ni] = zero;
#pragma unroll
    for (int c = 0; c < 2; c++) {
        short8 af[4], bf[4];
#pragma unroll
        for (int mi = 0; mi < 4; mi++)
            af[mi] = *(const short8*)&As[wm + mi * 16 + ln][c * 32 + quad * 8];
#pragma unroll
        for (int ni = 0; ni < 4; ni++)
            bf[ni] = *(const short8*)&Bs[wn + ni * 16 + ln][c * 32 + quad * 8];
#pragma unroll
        for (int mi = 0; mi < 4; mi++)
#pragma unroll
            for (int ni = 0; ni < 4; ni++)
                acc[mi][ni] = MFMA16(af[mi], bf[ni], acc[mi][ni]);
    }
#pragma unroll
    for (int mi = 0; mi < 4; mi++) {
        int row0 = m0 + wm + mi * 16 + quad * 4;
#pragma unroll
        for (int ni = 0; ni < 4; ni++) {
            int col = n0 + wn + ni * 16 + ln;
            if (!tr) {
                u16* Cp = c2p + (size_t)z * S * 512;
#pragma unroll
                for (int r = 0; r < 4; r++)
                    Cp[(size_t)(row0 + r) * 512 + col] = f2b(acc[mi][ni][r] * SC);
            } else {
                u16* Cp = p2cT + (size_t)z * 512 * S;
                ushort4 r4;
                r4.x = f2b(acc[mi][ni][0] * SC);
                r4.y = f2b(acc[mi][ni][1] * SC);
                r4.z = f2b(acc[mi][ni][2] * SC);
                r4.w = f2b(acc[mi][ni][3] * SC);
                *(ushort4*)(Cp + (size_t)col * S + row0) = r4;
            }
        }
    }
}

// ---------------- fused attention: software-pipelined gathers, no k-loop barriers ----------------
// Per tile: QK MFMA -> issue NEXT tile's 32 gather loads into regs -> consume current regs
// (exp2, fixed max 0) -> PV MFMA. Gather latency hides behind a full tile of compute.
template <int SPLIT>
__global__ __launch_bounds__(256) void k_attn(const u16* __restrict__ Qh,
                                              const u16* __restrict__ Kh,
                                              const u16* __restrict__ VT,
                                              const u16* __restrict__ c2p,
                                              const u16* __restrict__ p2cT,
                                              const short* __restrict__ idxTab,
                                              float* __restrict__ oP,
                                              float* __restrict__ lP,
                                              u16* __restrict__ ctx) {
    __shared__ short s_idx1[1024];
    __shared__ __align__(16) u16 p_lds[4][2][16][72];   // double-buffered per wave
    int tid = threadIdx.x;
    for (int i = tid; i < 1024; i += 256) s_idx1[i] = idxTab[i];
    __syncthreads();
    int lane = tid & 63, w = tid >> 6;
    int ln = lane & 15, quad = lane >> 4;
    int bx = blockIdx.x;
    int half = (SPLIT == 2) ? (bx & 1) : 0;
    int q0 = (SPLIT == 2) ? (bx >> 1) * 64 : bx * 64;
    int bh = blockIdx.y;
    int b = bh >> 4, h = bh & 15;
    int qs = q0 + w * 16;

    const u16* qptr = Qh + ((size_t)bh * S + qs + ln) * HD + quad * 8;
    short8 aq0 = *(const short8*)(qptr);
    short8 aq1 = *(const short8*)(qptr + 32);

    float4v o[4];
    float4v zero = {0.f, 0.f, 0.f, 0.f};
#pragma unroll
    for (int f = 0; f < 4; f++) o[f] = zero;
    float lrw[4] = {0.f, 0.f, 0.f, 0.f};

    const u16* c2pB = c2p + (size_t)bh * S * 512;
    const u16* p2cB = p2cT + (size_t)bh * 512 * S;
    const u16* kbase = Kh + (size_t)bh * S * HD + quad * 8;
    const u16* vbase = VT + (size_t)(b * 1024 + h * 64) * S + quad * 8;

    int qrow = qs + quad * 4;   // first of the 4 q rows this lane covers

    // issue the 32 gather loads for tile kk into (cv, pv) registers
    auto gather = [&](int kk, u16 (&cv)[4][4], u16 (&pv)[4][4]) {
#pragma unroll
        for (int f = 0; f < 4; f++) {
            int ki = kk + f * 16 + ln;
            int relb = qrow - ki;
#pragma unroll
            for (int r = 0; r < 4; r++) {
                int rel = relb + r;
                rel = rel < -512 ? -512 : (rel > 511 ? 511 : rel);
                int idx = (int)s_idx1[rel + 512];
                cv[f][r] = c2pB[(size_t)(qrow + r) * 512 + idx];
                pv[f][r] = p2cB[(size_t)idx * S + ki];
            }
        }
    };

    auto tile_step = [&](int buf, int kk, u16 (&cv)[4][4], u16 (&pv)[4][4],
                         u16 (&cvn)[4][4], u16 (&pvn)[4][4], int kkn, bool pref) {
        // ---- QK^T ----
        float4v sa[4];
#pragma unroll
        for (int f = 0; f < 4; f++) {
            const u16* kr = kbase + (size_t)(kk + f * 16 + ln) * HD;
            short8 b0 = *(const short8*)(kr);
            short8 b1 = *(const short8*)(kr + 32);
            float4v tt = zero;
            tt = MFMA16(aq0, b0, tt);
            tt = MFMA16(aq1, b1, tt);
            sa[f] = tt;
        }
        // ---- prefetch next tile's gathers (in flight across the rest of this tile) ----
        if (pref) gather(kkn, cvn, pvn);
        // ---- consume current gathers: bias + exp2 (fixed max 0) ----
#pragma unroll
        for (int f = 0; f < 4; f++)
#pragma unroll
            for (int r = 0; r < 4; r++) {
                float p = exp2f(sa[f][r] * SC + b2f(cv[f][r]) + b2f(pv[f][r]));
                lrw[r] += p;
                p_lds[w][buf][quad * 4 + r][f * 16 + ln] = f2b(p);
            }
        // ---- PV (own-wave LDS slice, no barrier) ----
        short8 ap0 = *(const short8*)&p_lds[w][buf][ln][quad * 8];
        short8 ap1 = *(const short8*)&p_lds[w][buf][ln][32 + quad * 8];
#pragma unroll
        for (int f = 0; f < 4; f++) {
            const u16* vr = vbase + (size_t)(f * 16 + ln) * S + kk;
            short8 v0 = *(const short8*)(vr);
            short8 v1 = *(const short8*)(vr + 32);
            o[f] = MFMA16(ap0, v0, o[f]);
            o[f] = MFMA16(ap1, v1, o[f]);
        }
    };

    const int NT = S / 64 / SPLIT;
    auto kk_of = [&](int t) { return (SPLIT == 2) ? (((t << 1) | half) << 6) : (t << 6); };

    u16 cva[4][4], pva[4][4], cvb[4][4], pvb[4][4];
    gather(kk_of(0), cva, pva);
    for (int t = 0; t < NT; t += 2) {
        tile_step(0, kk_of(t), cva, pva, cvb, pvb, kk_of(t + 1), true);
        tile_step(1, kk_of(t + 1), cvb, pvb, cva, pva,
                  kk_of(t + 2 < NT ? t + 2 : t + 1), t + 2 < NT);
    }

    // ---- single end-of-loop l reduction (within 16-lane quad) ----
#pragma unroll
    for (int r = 0; r < 4; r++) {
        lrw[r] += __shfl_xor(lrw[r], 1, 16);
        lrw[r] += __shfl_xor(lrw[r], 2, 16);
        lrw[r] += __shfl_xor(lrw[r], 4, 16);
        lrw[r] += __shfl_xor(lrw[r], 8, 16);
    }
    if (SPLIT == 1) {
        float inv_l[4];
#pragma unroll
        for (int r = 0; r < 4; r++) inv_l[r] = 1.f / lrw[r];
#pragma unroll
        for (int f = 0; f < 4; f++)
#pragma unroll
            for (int r = 0; r < 4; r++) {
                int qi = qs + quad * 4 + r;
                ctx[(size_t)(b * S + qi) * H + h * 64 + f * 16 + ln] = f2b(o[f][r] * inv_l[r]);
            }
    } else {
        float* oH = oP + (size_t)half * SP_OHALF;
#pragma unroll
        for (int f = 0; f < 4; f++)
#pragma unroll
            for (int r = 0; r < 4; r++) {
                int qi = qs + quad * 4 + r;
                oH[((size_t)bh * S + qi) * 64 + f * 16 + ln] = o[f][r];
            }
        if (ln == 0) {
            float* lH = lP + (size_t)half * SP_LHALF;
#pragma unroll
            for (int r = 0; r < 4; r++)
                lH[(size_t)bh * S + qs + quad * 4 + r] = lrw[r];
        }
    }
}

// ---------------- merge split-K partials -> ctx bf16 ----------------
__global__ __launch_bounds__(256) void k_merge(const float* __restrict__ oP,
                                               const float* __restrict__ lP,
                                               u16* __restrict__ ctx) {
    int t = blockIdx.x * 256 + threadIdx.x;
    int d4 = (t & 15) * 4;
    int h  = (t >> 4) & 15;
    int qq = (t >> 8) & 2047;
    int b  = t >> 19;
    int bh = b * 16 + h;
    size_t base = ((size_t)bh * S + qq) * 64 + d4;
    float4 o0 = *(const float4*)(oP + base);
    float4 o1 = *(const float4*)(oP + SP_OHALF + base);
    float l0 = lP[(size_t)bh * S + qq];
    float l1 = lP[SP_LHALF + (size_t)bh * S + qq];
    float inv = 1.f / (l0 + l1);
    ushort4 r4;
    r4.x = f2b((o0.x + o1.x) * inv);
    r4.y = f2b((o0.y + o1.y) * inv);
    r4.z = f2b((o0.z + o1.z) * inv);
    r4.w = f2b((o0.w + o1.w) * inv);
    *(ushort4*)(ctx + (((size_t)(b * S + qq)) * 16 + h) * 64 + d4) = r4;
}

// ---------------- launch ----------------
extern "C" void kernel_launch(void* const* d_in, const int* in_sizes, int n_in,
                              void* d_out, int out_size, void* d_ws, size_t ws_size,
                              hipStream_t stream) {
    const float* hs  = (const float*)d_in[0];
    const float* Wq  = (const float*)d_in[1];
    const float* bq  = (const float*)d_in[2];
    const float* Wk  = (const float*)d_in[3];
    const float* bk  = (const float*)d_in[4];
    const float* Wv  = (const float*)d_in[5];
    const float* bv  = (const float*)d_in[6];
    const float* Wo  = (const float*)d_in[7];
    const float* bo  = (const float*)d_in[8];
    const float* Wpk = (const float*)d_in[9];
    const float* bpk = (const float*)d_in[10];
    const float* Wpq = (const float*)d_in[11];
    const float* bpq = (const float*)d_in[12];
    const float* rel = (const float*)d_in[13];
    const float* lng = (const float*)d_in[14];
    const float* lnb = (const float*)d_in[15];

    char* ws = (char*)d_ws;
    u16* re_b   = (u16*)(ws + OFF_REB);
    u16* hs_b   = (u16*)(ws + OFF_HSB);
    u16* wt0    = (u16*)(ws + OFF_WT);
    u16* wt1    = (u16*)(ws + OFF_WT + 2097152ull);
    u16* wt2    = (u16*)(ws + OFF_WT + 2ull * 2097152ull);
    u16* wt3    = (u16*)(ws + OFF_WT + 3ull * 2097152ull);
    u16* wt4    = (u16*)(ws + OFF_WT + 4ull * 2097152ull);
    u16* wt5    = (u16*)(ws + OFF_WT + 5ull * 2097152ull);
    u16* Q_b    = (u16*)(ws + OFF_QB);
    u16* K_b    = (u16*)(ws + OFF_KB);
    u16* VT_b   = (u16*)(ws + OFF_VT);
    u16* posk_b = (u16*)(ws + OFF_PKB);
    u16* posq_b = (u16*)(ws + OFF_PQB);
    u16* c2p_b  = (u16*)(ws + OFF_C2P);
    u16* p2cT_b = (u16*)(ws + OFF_P2CT);
    u16* ctx_b  = (u16*)(ws + OFF_CTX);
    short* idx_t = (short*)(ws + OFF_IDX);
    float* oP   = (float*)(ws + OFF_SP);
    float* lP   = (float*)(ws + SP_LBASE);

    dim3 blk(256);
    k_build_idx<<<dim3(4), blk, 0, stream>>>(idx_t);
    k_ln<<<dim3(512), blk, 0, stream>>>(rel, lng, lnb, re_b);
    k_cast<<<dim3(4096), blk, 0, stream>>>(hs, hs_b);
    k_wt6<<<dim3(16, 16, 6), blk, 0, stream>>>(Wq, Wk, Wv, Wo, Wpk, Wpq,
                                               wt0, wt1, wt2, wt3, wt4, wt5);

    // projections
    k_qkv<<<dim3(32, 8, 3), blk, 0, stream>>>(hs_b, wt0, wt1, wt2, bq, bk, bv, Q_b, K_b, VT_b);
    k_gemm2_dual<0><<<dim3(4, 8, 2), blk, 0, stream>>>(re_b, wt4, wt5, bpk, bpq, posk_b, posq_b, H, H);

    // positional score tables (scale incl. log2e folded in)
    k_pos_both<<<dim3(16, 4, 64), blk, 0, stream>>>(Q_b, K_b, posk_b, posq_b, c2p_b, p2cT_b);

    // fused attention (split-K x2 interleaved when workspace allows)
    if (ws_size >= WS_NEED_SPLIT) {
        k_attn<2><<<dim3(64, 32), blk, 0, stream>>>(Q_b, K_b, VT_b, c2p_b, p2cT_b, idx_t, oP, lP, ctx_b);
        k_merge<<<dim3(4096), blk, 0, stream>>>(oP, lP, ctx_b);
    } else {
        k_attn<1><<<dim3(32, 32), blk, 0, stream>>>(Q_b, K_b, VT_b, c2p_b, p2cT_b, idx_t, oP, lP, ctx_b);
    }

    // output projection (fp32 out)
    k_gemm2<1><<<dim3(32, 8), blk, 0, stream>>>(ctx_b, wt3, bo, d_out, H, H);
}

// Round 8
// 549.289 us; speedup vs baseline: 1.0167x; 1.0167x over previous
//
#include <hip/hip_runtime.h>

typedef unsigned short u16;
typedef __attribute__((ext_vector_type(8))) short short8;
typedef __attribute__((ext_vector_type(4))) float float4v;

#define MFMA16(a, b, c) __builtin_amdgcn_mfma_f32_16x16x32_bf16((a), (b), (c), 0, 0, 0)

// ---------------- helpers ----------------
__device__ __forceinline__ u16 f2b(float x) {
    union { float f; unsigned u; } v; v.f = x;
    unsigned r = v.u + 0x7FFFu + ((v.u >> 16) & 1u);   // RNE
    return (u16)(r >> 16);
}
__device__ __forceinline__ float b2f(u16 u) {
    union { unsigned u; float f; } v; v.u = ((unsigned)u) << 16; return v.f;
}

// constants
#define NH 16
#define S  2048
#define HD 64
#define H  1024
// scale = 1/sqrt(192) * log2(e)  (exp -> exp2 folded into all score terms)
#define SC 0.10412111829775301f

// ---------------- workspace offsets (bytes) ----------------
#define OFF_REB   0ull
#define OFF_HSB   (OFF_REB  + 1048576ull)
#define OFF_WT    (OFF_HSB  + 8388608ull)
#define OFF_QB    (OFF_WT   + 12582912ull)
#define OFF_KB    (OFF_QB   + 8388608ull)
#define OFF_VT    (OFF_KB   + 8388608ull)
#define OFF_PKB   (OFF_VT   + 8388608ull)
#define OFF_PQB   (OFF_PKB  + 1048576ull)
#define OFF_C2P   (OFF_PQB  + 1048576ull)                // 64 MB [bh][q][512]
#define OFF_P2CT  (OFF_C2P  + 67108864ull)               // 64 MB [bh][p][2048]
#define OFF_CTX   (OFF_P2CT + 67108864ull)
#define OFF_IDX   (OFF_CTX  + 8388608ull)
#define OFF_SP    (OFF_IDX  + 8192ull)                   // split-K partials
#define SP_OHALF  4194304ull                             // floats per half (32*2048*64)
#define SP_LBASE  (OFF_SP + 67108864ull)
#define SP_LHALF  65536ull
#define WS_NEED_SPLIT (SP_LBASE + 524288ull)             // ~248 MB

// ---------------- idx table for rel in [-512, 511] ----------------
// idx(rel<=-512)==0, idx(rel>=506)==511, idx monotone => clamping rel to [-512,511] is EXACT.
__global__ void k_build_idx(short* __restrict__ t) {
    int i = blockIdx.x * 256 + threadIdx.x;
    if (i >= 1024) return;
    int rel = i - 512;
    float fr = (float)rel;
    float abs_pos = (rel < 128 && rel > -128) ? 127.0f : fabsf(fr);
    const float LOGC = 1.3843393262841284f;  // float32(ln(511/128))
    float log_pos = ceilf(logf(abs_pos * (1.0f / 128.0f)) / LOGC * 127.0f) + 128.0f;
    float sgn = (fr > 0.f) ? 1.f : ((fr < 0.f) ? -1.f : 0.f);
    float bf = (abs_pos <= 128.0f) ? fr : log_pos * sgn;
    int idx = (int)bf + 256;
    idx = idx < 0 ? 0 : (idx > 511 ? 511 : idx);
    t[i] = (short)idx;
}

// ---------------- LayerNorm of rel_emb -> bf16 ----------------
__global__ __launch_bounds__(256) void k_ln(const float* __restrict__ re,
                                            const float* __restrict__ g,
                                            const float* __restrict__ be,
                                            u16* __restrict__ out) {
    int row = blockIdx.x;
    const float4* x4 = (const float4*)(re + (size_t)row * H);
    int tid = threadIdx.x;
    float4 vv = x4[tid];
    float s = vv.x + vv.y + vv.z + vv.w;
    float s2 = vv.x * vv.x + vv.y * vv.y + vv.z * vv.z + vv.w * vv.w;
    for (int m = 1; m < 64; m <<= 1) {
        s += __shfl_xor(s, m, 64);
        s2 += __shfl_xor(s2, m, 64);
    }
    __shared__ float as[4], as2[4];
    if ((tid & 63) == 0) { as[tid >> 6] = s; as2[tid >> 6] = s2; }
    __syncthreads();
    s = as[0] + as[1] + as[2] + as[3];
    s2 = as2[0] + as2[1] + as2[2] + as2[3];
    float mu = s * (1.f / 1024.f);
    float var = s2 * (1.f / 1024.f) - mu * mu;
    float rstd = rsqrtf(var + 1e-5f);
    float4 gg = ((const float4*)g)[tid];
    float4 bb = ((const float4*)be)[tid];
    ushort4 r4;
    r4.x = f2b((vv.x - mu) * rstd * gg.x + bb.x);
    r4.y = f2b((vv.y - mu) * rstd * gg.y + bb.y);
    r4.z = f2b((vv.z - mu) * rstd * gg.z + bb.z);
    r4.w = f2b((vv.w - mu) * rstd * gg.w + bb.w);
    ((ushort4*)(out + (size_t)row * H))[tid] = r4;
}

// ---------------- fp32 -> bf16 cast ----------------
__global__ __launch_bounds__(256) void k_cast(const float* __restrict__ x, u16* __restrict__ y) {
    int i = blockIdx.x * 256 + threadIdx.x;
    float4 v = ((const float4*)x)[i];
    ushort4 r;
    r.x = f2b(v.x); r.y = f2b(v.y); r.z = f2b(v.z); r.w = f2b(v.w);
    ((ushort4*)y)[i] = r;
}

// ---------------- 6x weight transpose + cast ----------------
__global__ __launch_bounds__(256) void k_wt6(const float* __restrict__ W0, const float* __restrict__ W1,
                                             const float* __restrict__ W2, const float* __restrict__ W3,
                                             const float* __restrict__ W4, const float* __restrict__ W5,
                                             u16* __restrict__ T0, u16* __restrict__ T1,
                                             u16* __restrict__ T2, u16* __restrict__ T3,
                                             u16* __restrict__ T4, u16* __restrict__ T5) {
    const float* W; u16* WT;
    switch (blockIdx.z) {
        case 0: W = W0; WT = T0; break;
        case 1: W = W1; WT = T1; break;
        case 2: W = W2; WT = T2; break;
        case 3: W = W3; WT = T3; break;
        case 4: W = W4; WT = T4; break;
        default: W = W5; WT = T5; break;
    }
    __shared__ float t[64][65];
    int k0 = blockIdx.x * 64, n0 = blockIdx.y * 64;
    int tid = threadIdx.x;
#pragma unroll
    for (int i = 0; i < 16; i++) {
        int lin = tid + 256 * i;
        int r = lin >> 6, c = lin & 63;
        t[r][c] = W[(size_t)(k0 + r) * H + n0 + c];
    }
    __syncthreads();
#pragma unroll
    for (int i = 0; i < 16; i++) {
        int lin = tid + 256 * i;
        int r = lin >> 6, c = lin & 63;
        WT[(size_t)(n0 + r) * H + k0 + c] = f2b(t[c][r]);
    }
}

// ---------------- 128x128-tile GEMM core ----------------
// MODE 0: bf16 row-major; MODE 1: f32 row-major;
// MODE 2: bf16 VT layout (b*1024+n)*2048 + m ; MODE 3: bf16 head-major ((b*16+h)*2048+m)*64+d
template <int MODE>
__device__ __forceinline__ void gemm2_body(const u16* __restrict__ A,
                                           const u16* __restrict__ Bt,
                                           const float* __restrict__ bias,
                                           void* __restrict__ C, int N, int K) {
    __shared__ __align__(16) u16 As[128 * 32];
    __shared__ __align__(16) u16 Bs[128 * 32];
    int tid = threadIdx.x;
    int lane = tid & 63, w = tid >> 6;
    int ln = lane & 15, quad = lane >> 4;
    int m0 = blockIdx.x * 128, n0 = blockIdx.y * 128;
    int wm = (w >> 1) * 64, wn = (w & 1) * 64;
    float4v acc[4][4];
    float4v zero = {0.f, 0.f, 0.f, 0.f};
#pragma unroll
    for (int mi = 0; mi < 4; mi++)
#pragma unroll
        for (int ni = 0; ni < 4; ni++) acc[mi][ni] = zero;

    int r1 = tid >> 2, o1 = (tid & 3) * 8;
    const u16* ga1 = A + (size_t)(m0 + r1) * K + o1;
    const u16* gb1 = Bt + (size_t)(n0 + r1) * K + o1;
    u16* sa1 = &As[r1 * 32 + o1];
    u16* sb1 = &Bs[r1 * 32 + o1];
    size_t step2 = (size_t)64 * K;

    for (int k0 = 0; k0 < K; k0 += 32) {
        short8 va1 = *(const short8*)(ga1 + k0);
        short8 va2 = *(const short8*)(ga1 + step2 + k0);
        short8 vb1 = *(const short8*)(gb1 + k0);
        short8 vb2 = *(const short8*)(gb1 + step2 + k0);
        __syncthreads();
        *(short8*)sa1 = va1; *(short8*)(sa1 + 2048) = va2;
        *(short8*)sb1 = vb1; *(short8*)(sb1 + 2048) = vb2;
        __syncthreads();
        short8 af[4], bf[4];
#pragma unroll
        for (int mi = 0; mi < 4; mi++)
            af[mi] = *(const short8*)&As[(wm + mi * 16 + ln) * 32 + quad * 8];
#pragma unroll
        for (int ni = 0; ni < 4; ni++)
            bf[ni] = *(const short8*)&Bs[(wn + ni * 16 + ln) * 32 + quad * 8];
#pragma unroll
        for (int mi = 0; mi < 4; mi++)
#pragma unroll
            for (int ni = 0; ni < 4; ni++)
                acc[mi][ni] = MFMA16(af[mi], bf[ni], acc[mi][ni]);
    }

#pragma unroll
    for (int mi = 0; mi < 4; mi++) {
        int row0 = m0 + wm + mi * 16 + quad * 4;
#pragma unroll
        for (int ni = 0; ni < 4; ni++) {
            int col = n0 + wn + ni * 16 + ln;
            float bv = bias[col];
            if (MODE == 0) {
                u16* Cb = (u16*)C;
#pragma unroll
                for (int r = 0; r < 4; r++)
                    Cb[(size_t)(row0 + r) * N + col] = f2b(acc[mi][ni][r] + bv);
            } else if (MODE == 1) {
                float* Cf = (float*)C;
#pragma unroll
                for (int r = 0; r < 4; r++)
                    Cf[(size_t)(row0 + r) * N + col] = acc[mi][ni][r] + bv;
            } else if (MODE == 2) {
                u16* Cb = (u16*)C;
                int bb = row0 >> 11, s = row0 & 2047;
                ushort4 r4;
                r4.x = f2b(acc[mi][ni][0] + bv);
                r4.y = f2b(acc[mi][ni][1] + bv);
                r4.z = f2b(acc[mi][ni][2] + bv);
                r4.w = f2b(acc[mi][ni][3] + bv);
                *(ushort4*)(Cb + ((size_t)(bb * 1024 + col)) * 2048 + s) = r4;
            } else {
                u16* Cb = (u16*)C;
                int bb = row0 >> 11, s = row0 & 2047;
                int h = col >> 6, d = col & 63;
#pragma unroll
                for (int r = 0; r < 4; r++)
                    Cb[((size_t)(bb * 16 + h) * 2048 + s + r) * 64 + d] = f2b(acc[mi][ni][r] + bv);
            }
        }
    }
}

template <int MODE>
__global__ __launch_bounds__(256) void k_gemm2(const u16* __restrict__ A, const u16* __restrict__ Bt,
                                               const float* __restrict__ bias, void* __restrict__ C,
                                               int N, int K) {
    gemm2_body<MODE>(A, Bt, bias, C, N, K);
}

template <int MODE>
__global__ __launch_bounds__(256) void k_gemm2_dual(const u16* __restrict__ A,
                                                    const u16* __restrict__ Bt0, const u16* __restrict__ Bt1,
                                                    const float* __restrict__ b0, const float* __restrict__ b1,
                                                    void* __restrict__ C0, void* __restrict__ C1,
                                                    int N, int K) {
    if (blockIdx.z == 0) gemm2_body<MODE>(A, Bt0, b0, C0, N, K);
    else                 gemm2_body<MODE>(A, Bt1, b1, C1, N, K);
}

// Q/K/V projections in one launch (z: 0=Q head-major, 1=K head-major, 2=V transposed)
__global__ __launch_bounds__(256) void k_qkv(const u16* __restrict__ A,
                                             const u16* __restrict__ W0, const u16* __restrict__ W1,
                                             const u16* __restrict__ W2,
                                             const float* __restrict__ b0, const float* __restrict__ b1,
                                             const float* __restrict__ b2,
                                             u16* __restrict__ Q, u16* __restrict__ K, u16* __restrict__ VT) {
    if (blockIdx.z == 0)      gemm2_body<3>(A, W0, b0, Q, H, H);
    else if (blockIdx.z == 1) gemm2_body<3>(A, W1, b1, K, H, H);
    else                      gemm2_body<2>(A, W2, b2, VT, H, H);
}

// ---------------- both positional score tables, one launch ----------------
__global__ __launch_bounds__(256) void k_pos_both(const u16* __restrict__ Qh, const u16* __restrict__ Kh,
                                                  const u16* __restrict__ pk, const u16* __restrict__ pq,
                                                  u16* __restrict__ c2p, u16* __restrict__ p2cT) {
    __shared__ __align__(16) u16 As[128][72];
    __shared__ __align__(16) u16 Bs[128][72];
    int tid = threadIdx.x;
    int lane = tid & 63, w = tid >> 6;
    int ln = lane & 15, quad = lane >> 4;
    int tr = blockIdx.z & 1, z = blockIdx.z >> 1, h = z & 15;
    int m0 = blockIdx.x * 128, n0 = blockIdx.y * 128;
    const u16* A = (tr ? Kh : Qh) + (size_t)z * S * HD;
    const u16* B = (tr ? pq : pk) + h * 64;
    int sr = tid >> 1, scb = (tid & 1) * 32;
    {
        const u16* ga = A + (size_t)(m0 + sr) * HD + scb;
        const u16* gb = B + (size_t)(n0 + sr) * H + scb;
#pragma unroll
        for (int j = 0; j < 4; j++) {
            *(short8*)&As[sr][scb + j * 8] = *(const short8*)(ga + j * 8);
            *(short8*)&Bs[sr][scb + j * 8] = *(const short8*)(gb + j * 8);
        }
    }
    __syncthreads();
    int wm = (w >> 1) * 64, wn = (w & 1) * 64;
    float4v acc[4][4];
    float4v zero = {0.f, 0.f, 0.f, 0.f};
#pragma unroll
    for (int mi = 0; mi < 4; mi++)
#pragma unroll
        for (int ni = 0; ni < 4; ni++) acc[mi][ni] = zero;
#pragma unroll
    for (int c = 0; c < 2; c++) {
        short8 af[4], bf[4];
#pragma unroll
        for (int mi = 0; mi < 4; mi++)
            af[mi] = *(const short8*)&As[wm + mi * 16 + ln][c * 32 + quad * 8];
#pragma unroll
        for (int ni = 0; ni < 4; ni++)
            bf[ni] = *(const short8*)&Bs[wn + ni * 16 + ln][c * 32 + quad * 8];
#pragma unroll
        for (int mi = 0; mi < 4; mi++)
#pragma unroll
            for (int ni = 0; ni < 4; ni++)
                acc[mi][ni] = MFMA16(af[mi], bf[ni], acc[mi][ni]);
    }
#pragma unroll
    for (int mi = 0; mi < 4; mi++) {
        int row0 = m0 + wm + mi * 16 + quad * 4;
#pragma unroll
        for (int ni = 0; ni < 4; ni++) {
            int col = n0 + wn + ni * 16 + ln;
            if (!tr) {
                u16* Cp = c2p + (size_t)z * S * 512;
#pragma unroll
                for (int r = 0; r < 4; r++)
                    Cp[(size_t)(row0 + r) * 512 + col] = f2b(acc[mi][ni][r] * SC);
            } else {
                u16* Cp = p2cT + (size_t)z * 512 * S;
                ushort4 r4;
                r4.x = f2b(acc[mi][ni][0] * SC);
                r4.y = f2b(acc[mi][ni][1] * SC);
                r4.z = f2b(acc[mi][ni][2] * SC);
                r4.w = f2b(acc[mi][ni][3] * SC);
                *(ushort4*)(Cp + (size_t)col * S + row0) = r4;
            }
        }
    }
}

// ---------------- fused attention: occupancy-first (>=4 waves/SIMD), inline gathers ----------------
// Registers minimized (no prefetch buffers, no staging); latency hidden by resident waves.
template <int SPLIT>
__global__ __launch_bounds__(256, 4) void k_attn(const u16* __restrict__ Qh,
                                                 const u16* __restrict__ Kh,
                                                 const u16* __restrict__ VT,
                                                 const u16* __restrict__ c2p,
                                                 const u16* __restrict__ p2cT,
                                                 const short* __restrict__ idxTab,
                                                 float* __restrict__ oP,
                                                 float* __restrict__ lP,
                                                 u16* __restrict__ ctx) {
    __shared__ short s_idx1[1024];
    __shared__ __align__(16) u16 p_lds[4][16][72];
    int tid = threadIdx.x;
    for (int i = tid; i < 1024; i += 256) s_idx1[i] = idxTab[i];
    __syncthreads();
    int lane = tid & 63, w = tid >> 6;
    int ln = lane & 15, quad = lane >> 4;
    int bx = blockIdx.x;
    int half = (SPLIT == 2) ? (bx & 1) : 0;
    int q0 = (SPLIT == 2) ? (bx >> 1) * 64 : bx * 64;
    int bh = blockIdx.y;
    int b = bh >> 4, h = bh & 15;
    int qs = q0 + w * 16;

    const u16* qptr = Qh + ((size_t)bh * S + qs + ln) * HD + quad * 8;
    short8 aq0 = *(const short8*)(qptr);
    short8 aq1 = *(const short8*)(qptr + 32);

    float4v o[4];
    float4v zero = {0.f, 0.f, 0.f, 0.f};
#pragma unroll
    for (int f = 0; f < 4; f++) o[f] = zero;
    float lrw[4] = {0.f, 0.f, 0.f, 0.f};

    const u16* c2pB = c2p + (size_t)bh * S * 512;
    const u16* p2cB = p2cT + (size_t)bh * 512 * S;
    const u16* kbase = Kh + (size_t)bh * S * HD + quad * 8;
    const u16* vbase = VT + (size_t)(b * 1024 + h * 64) * S + quad * 8;
    int qrow = qs + quad * 4;

    const int NT = S / 64 / SPLIT;
    for (int t = 0; t < NT; t++) {
        int kk = (SPLIT == 2) ? (((t << 1) | half) << 6) : (t << 6);
        // ---- QK^T ----
        float4v sa[4];
#pragma unroll
        for (int f = 0; f < 4; f++) {
            const u16* kr = kbase + (size_t)(kk + f * 16 + ln) * HD;
            short8 b0 = *(const short8*)(kr);
            short8 b1 = *(const short8*)(kr + 32);
            float4v tt = zero;
            tt = MFMA16(aq0, b0, tt);
            tt = MFMA16(aq1, b1, tt);
            sa[f] = tt;
        }
        // ---- positional bias + exp2 (fixed max 0) ----
        int rel0 = q0 - kk;
        if (rel0 >= 569 || rel0 <= -633) {
            // far tile: bucket constant (0 or 511) across whole 64x64 tile
            int idx = rel0 > 0 ? 511 : 0;
            float cvr[4];
#pragma unroll
            for (int r = 0; r < 4; r++)
                cvr[r] = b2f(c2pB[(size_t)(qrow + r) * 512 + idx]);
            const u16* prow = p2cB + (size_t)idx * S + kk;
#pragma unroll
            for (int f = 0; f < 4; f++) {
                float pv = b2f(prow[f * 16 + ln]);
#pragma unroll
                for (int r = 0; r < 4; r++) {
                    float p = exp2f(sa[f][r] * SC + cvr[r] + pv);
                    lrw[r] += p;
                    p_lds[w][quad * 4 + r][f * 16 + ln] = f2b(p);
                }
            }
        } else {
            // near tile: per-element gathers (no barriers; latency hidden by occupancy)
#pragma unroll
            for (int f = 0; f < 4; f++) {
                int ki = kk + f * 16 + ln;
                int relb = qrow - ki;
#pragma unroll
                for (int r = 0; r < 4; r++) {
                    int rel = relb + r;
                    rel = rel < -512 ? -512 : (rel > 511 ? 511 : rel);
                    int idx = (int)s_idx1[rel + 512];
                    float cv = b2f(c2pB[(size_t)(qrow + r) * 512 + idx]);
                    float pv = b2f(p2cB[(size_t)idx * S + ki]);
                    float p = exp2f(sa[f][r] * SC + cv + pv);
                    lrw[r] += p;
                    p_lds[w][quad * 4 + r][f * 16 + ln] = f2b(p);
                }
            }
        }
        // ---- PV (own-wave LDS slice, no barrier) ----
        short8 ap0 = *(const short8*)&p_lds[w][ln][quad * 8];
        short8 ap1 = *(const short8*)&p_lds[w][ln][32 + quad * 8];
#pragma unroll
        for (int f = 0; f < 4; f++) {
            const u16* vr = vbase + (size_t)(f * 16 + ln) * S + kk;
            short8 v0 = *(const short8*)(vr);
            short8 v1 = *(const short8*)(vr + 32);
            o[f] = MFMA16(ap0, v0, o[f]);
            o[f] = MFMA16(ap1, v1, o[f]);
        }
    }
    // ---- single end-of-loop l reduction (within 16-lane quad) ----
#pragma unroll
    for (int r = 0; r < 4; r++) {
        lrw[r] += __shfl_xor(lrw[r], 1, 16);
        lrw[r] += __shfl_xor(lrw[r], 2, 16);
        lrw[r] += __shfl_xor(lrw[r], 4, 16);
        lrw[r] += __shfl_xor(lrw[r], 8, 16);
    }
    if (SPLIT == 1) {
        float inv_l[4];
#pragma unroll
        for (int r = 0; r < 4; r++) inv_l[r] = 1.f / lrw[r];
#pragma unroll
        for (int f = 0; f < 4; f++)
#pragma unroll
            for (int r = 0; r < 4; r++) {
                int qi = qs + quad * 4 + r;
                ctx[(size_t)(b * S + qi) * H + h * 64 + f * 16 + ln] = f2b(o[f][r] * inv_l[r]);
            }
    } else {
        float* oH = oP + (size_t)half * SP_OHALF;
#pragma unroll
        for (int f = 0; f < 4; f++)
#pragma unroll
            for (int r = 0; r < 4; r++) {
                int qi = qs + quad * 4 + r;
                oH[((size_t)bh * S + qi) * 64 + f * 16 + ln] = o[f][r];
            }
        if (ln == 0) {
            float* lH = lP + (size_t)half * SP_LHALF;
#pragma unroll
            for (int r = 0; r < 4; r++)
                lH[(size_t)bh * S + qs + quad * 4 + r] = lrw[r];
        }
    }
}

// ---------------- merge split-K partials -> ctx bf16 ----------------
__global__ __launch_bounds__(256) void k_merge(const float* __restrict__ oP,
                                               const float* __restrict__ lP,
                                               u16* __restrict__ ctx) {
    int t = blockIdx.x * 256 + threadIdx.x;
    int d4 = (t & 15) * 4;
    int h  = (t >> 4) & 15;
    int qq = (t >> 8) & 2047;
    int b  = t >> 19;
    int bh = b * 16 + h;
    size_t base = ((size_t)bh * S + qq) * 64 + d4;
    float4 o0 = *(const float4*)(oP + base);
    float4 o1 = *(const float4*)(oP + SP_OHALF + base);
    float l0 = lP[(size_t)bh * S + qq];
    float l1 = lP[SP_LHALF + (size_t)bh * S + qq];
    float inv = 1.f / (l0 + l1);
    ushort4 r4;
    r4.x = f2b((o0.x + o1.x) * inv);
    r4.y = f2b((o0.y + o1.y) * inv);
    r4.z = f2b((o0.z + o1.z) * inv);
    r4.w = f2b((o0.w + o1.w) * inv);
    *(ushort4*)(ctx + (((size_t)(b * S + qq)) * 16 + h) * 64 + d4) = r4;
}

// ---------------- launch ----------------
extern "C" void kernel_launch(void* const* d_in, const int* in_sizes, int n_in,
                              void* d_out, int out_size, void* d_ws, size_t ws_size,
                              hipStream_t stream) {
    const float* hs  = (const float*)d_in[0];
    const float* Wq  = (const float*)d_in[1];
    const float* bq  = (const float*)d_in[2];
    const float* Wk  = (const float*)d_in[3];
    const float* bk  = (const float*)d_in[4];
    const float* Wv  = (const float*)d_in[5];
    const float* bv  = (const float*)d_in[6];
    const float* Wo  = (const float*)d_in[7];
    const float* bo  = (const float*)d_in[8];
    const float* Wpk = (const float*)d_in[9];
    const float* bpk = (const float*)d_in[10];
    const float* Wpq = (const float*)d_in[11];
    const float* bpq = (const float*)d_in[12];
    const float* rel = (const float*)d_in[13];
    const float* lng = (const float*)d_in[14];
    const float* lnb = (const float*)d_in[15];

    char* ws = (char*)d_ws;
    u16* re_b   = (u16*)(ws + OFF_REB);
    u16* hs_b   = (u16*)(ws + OFF_HSB);
    u16* wt0    = (u16*)(ws + OFF_WT);
    u16* wt1    = (u16*)(ws + OFF_WT + 2097152ull);
    u16* wt2    = (u16*)(ws + OFF_WT + 2ull * 2097152ull);
    u16* wt3    = (u16*)(ws + OFF_WT + 3ull * 2097152ull);
    u16* wt4    = (u16*)(ws + OFF_WT + 4ull * 2097152ull);
    u16* wt5    = (u16*)(ws + OFF_WT + 5ull * 2097152ull);
    u16* Q_b    = (u16*)(ws + OFF_QB);
    u16* K_b    = (u16*)(ws + OFF_KB);
    u16* VT_b   = (u16*)(ws + OFF_VT);
    u16* posk_b = (u16*)(ws + OFF_PKB);
    u16* posq_b = (u16*)(ws + OFF_PQB);
    u16* c2p_b  = (u16*)(ws + OFF_C2P);
    u16* p2cT_b = (u16*)(ws + OFF_P2CT);
    u16* ctx_b  = (u16*)(ws + OFF_CTX);
    short* idx_t = (short*)(ws + OFF_IDX);
    float* oP   = (float*)(ws + OFF_SP);
    float* lP   = (float*)(ws + SP_LBASE);

    dim3 blk(256);
    k_build_idx<<<dim3(4), blk, 0, stream>>>(idx_t);
    k_ln<<<dim3(512), blk, 0, stream>>>(rel, lng, lnb, re_b);
    k_cast<<<dim3(4096), blk, 0, stream>>>(hs, hs_b);
    k_wt6<<<dim3(16, 16, 6), blk, 0, stream>>>(Wq, Wk, Wv, Wo, Wpk, Wpq,
                                               wt0, wt1, wt2, wt3, wt4, wt5);

    // projections
    k_qkv<<<dim3(32, 8, 3), blk, 0, stream>>>(hs_b, wt0, wt1, wt2, bq, bk, bv, Q_b, K_b, VT_b);
    k_gemm2_dual<0><<<dim3(4, 8, 2), blk, 0, stream>>>(re_b, wt4, wt5, bpk, bpq, posk_b, posq_b, H, H);

    // positional score tables (scale incl. log2e folded in)
    k_pos_both<<<dim3(16, 4, 64), blk, 0, stream>>>(Q_b, K_b, posk_b, posq_b, c2p_b, p2cT_b);

    // fused attention (split-K x2 interleaved when workspace allows)
    if (ws_size >= WS_NEED_SPLIT) {
        k_attn<2><<<dim3(64, 32), blk, 0, stream>>>(Q_b, K_b, VT_b, c2p_b, p2cT_b, idx_t, oP, lP, ctx_b);
        k_merge<<<dim3(4096), blk, 0, stream>>>(oP, lP, ctx_b);
    } else {
        k_attn<1><<<dim3(32, 32), blk, 0, stream>>>(Q_b, K_b, VT_b, c2p_b, p2cT_b, idx_t, oP, lP, ctx_b);
    }

    // output projection (fp32 out)
    k_gemm2<1><<<dim3(32, 8), blk, 0, stream>>>(ctx_b, wt3, bo, d_out, H, H);
}

// Round 9
// 402.783 us; speedup vs baseline: 1.3865x; 1.3637x over previous
//
#include <hip/hip_runtime.h>

typedef unsigned short u16;
typedef __attribute__((ext_vector_type(8))) short short8;
typedef __attribute__((ext_vector_type(4))) float float4v;

#define MFMA16(a, b, c) __builtin_amdgcn_mfma_f32_16x16x32_bf16((a), (b), (c), 0, 0, 0)

// ---------------- helpers ----------------
__device__ __forceinline__ u16 f2b(float x) {
    union { float f; unsigned u; } v; v.f = x;
    unsigned r = v.u + 0x7FFFu + ((v.u >> 16) & 1u);   // RNE
    return (u16)(r >> 16);
}
__device__ __forceinline__ float b2f(u16 u) {
    union { unsigned u; float f; } v; v.u = ((unsigned)u) << 16; return v.f;
}

// constants
#define NH 16
#define S  2048
#define HD 64
#define H  1024
// scale = 1/sqrt(192) * log2(e)  (exp -> exp2 folded into all score terms)
#define SC 0.10412111829775301f

// ---------------- workspace offsets (bytes) ----------------
#define OFF_REB   0ull
#define OFF_HSB   (OFF_REB  + 1048576ull)
#define OFF_WT    (OFF_HSB  + 8388608ull)
#define OFF_QB    (OFF_WT   + 12582912ull)
#define OFF_KB    (OFF_QB   + 8388608ull)
#define OFF_VT    (OFF_KB   + 8388608ull)
#define OFF_PKB   (OFF_VT   + 8388608ull)
#define OFF_PQB   (OFF_PKB  + 1048576ull)
#define OFF_C2P   (OFF_PQB  + 1048576ull)                // 64 MB [bh][q][512]
#define OFF_P2CT  (OFF_C2P  + 67108864ull)               // 64 MB [bh][p][2048]
#define OFF_CTX   (OFF_P2CT + 67108864ull)
#define OFF_IDX   (OFF_CTX  + 8388608ull)
#define OFF_SP    (OFF_IDX  + 8192ull)                   // split-K partials
#define SP_OHALF  4194304ull                             // floats per half (32*2048*64)
#define SP_LBASE  (OFF_SP + 67108864ull)
#define SP_LHALF  65536ull
#define WS_NEED_SPLIT (SP_LBASE + 524288ull)             // ~248 MB

// ---------------- idx table for rel in [-512, 511] ----------------
// idx(rel<=-512)==0, idx(rel>=506)==511, idx monotone => clamping rel to [-512,511] is EXACT.
__global__ void k_build_idx(short* __restrict__ t) {
    int i = blockIdx.x * 256 + threadIdx.x;
    if (i >= 1024) return;
    int rel = i - 512;
    float fr = (float)rel;
    float abs_pos = (rel < 128 && rel > -128) ? 127.0f : fabsf(fr);
    const float LOGC = 1.3843393262841284f;  // float32(ln(511/128))
    float log_pos = ceilf(logf(abs_pos * (1.0f / 128.0f)) / LOGC * 127.0f) + 128.0f;
    float sgn = (fr > 0.f) ? 1.f : ((fr < 0.f) ? -1.f : 0.f);
    float bf = (abs_pos <= 128.0f) ? fr : log_pos * sgn;
    int idx = (int)bf + 256;
    idx = idx < 0 ? 0 : (idx > 511 ? 511 : idx);
    t[i] = (short)idx;
}

// ---------------- LayerNorm of rel_emb -> bf16 ----------------
__global__ __launch_bounds__(256) void k_ln(const float* __restrict__ re,
                                            const float* __restrict__ g,
                                            const float* __restrict__ be,
                                            u16* __restrict__ out) {
    int row = blockIdx.x;
    const float4* x4 = (const float4*)(re + (size_t)row * H);
    int tid = threadIdx.x;
    float4 vv = x4[tid];
    float s = vv.x + vv.y + vv.z + vv.w;
    float s2 = vv.x * vv.x + vv.y * vv.y + vv.z * vv.z + vv.w * vv.w;
    for (int m = 1; m < 64; m <<= 1) {
        s += __shfl_xor(s, m, 64);
        s2 += __shfl_xor(s2, m, 64);
    }
    __shared__ float as[4], as2[4];
    if ((tid & 63) == 0) { as[tid >> 6] = s; as2[tid >> 6] = s2; }
    __syncthreads();
    s = as[0] + as[1] + as[2] + as[3];
    s2 = as2[0] + as2[1] + as2[2] + as2[3];
    float mu = s * (1.f / 1024.f);
    float var = s2 * (1.f / 1024.f) - mu * mu;
    float rstd = rsqrtf(var + 1e-5f);
    float4 gg = ((const float4*)g)[tid];
    float4 bb = ((const float4*)be)[tid];
    ushort4 r4;
    r4.x = f2b((vv.x - mu) * rstd * gg.x + bb.x);
    r4.y = f2b((vv.y - mu) * rstd * gg.y + bb.y);
    r4.z = f2b((vv.z - mu) * rstd * gg.z + bb.z);
    r4.w = f2b((vv.w - mu) * rstd * gg.w + bb.w);
    ((ushort4*)(out + (size_t)row * H))[tid] = r4;
}

// ---------------- fp32 -> bf16 cast ----------------
__global__ __launch_bounds__(256) void k_cast(const float* __restrict__ x, u16* __restrict__ y) {
    int i = blockIdx.x * 256 + threadIdx.x;
    float4 v = ((const float4*)x)[i];
    ushort4 r;
    r.x = f2b(v.x); r.y = f2b(v.y); r.z = f2b(v.z); r.w = f2b(v.w);
    ((ushort4*)y)[i] = r;
}

// ---------------- 6x weight transpose + cast ----------------
__global__ __launch_bounds__(256) void k_wt6(const float* __restrict__ W0, const float* __restrict__ W1,
                                             const float* __restrict__ W2, const float* __restrict__ W3,
                                             const float* __restrict__ W4, const float* __restrict__ W5,
                                             u16* __restrict__ T0, u16* __restrict__ T1,
                                             u16* __restrict__ T2, u16* __restrict__ T3,
                                             u16* __restrict__ T4, u16* __restrict__ T5) {
    const float* W; u16* WT;
    switch (blockIdx.z) {
        case 0: W = W0; WT = T0; break;
        case 1: W = W1; WT = T1; break;
        case 2: W = W2; WT = T2; break;
        case 3: W = W3; WT = T3; break;
        case 4: W = W4; WT = T4; break;
        default: W = W5; WT = T5; break;
    }
    __shared__ float t[64][65];
    int k0 = blockIdx.x * 64, n0 = blockIdx.y * 64;
    int tid = threadIdx.x;
#pragma unroll
    for (int i = 0; i < 16; i++) {
        int lin = tid + 256 * i;
        int r = lin >> 6, c = lin & 63;
        t[r][c] = W[(size_t)(k0 + r) * H + n0 + c];
    }
    __syncthreads();
#pragma unroll
    for (int i = 0; i < 16; i++) {
        int lin = tid + 256 * i;
        int r = lin >> 6, c = lin & 63;
        WT[(size_t)(n0 + r) * H + k0 + c] = f2b(t[c][r]);
    }
}

// ---------------- 128x128-tile GEMM core ----------------
// MODE 0: bf16 row-major; MODE 1: f32 row-major;
// MODE 2: bf16 VT layout (b*1024+n)*2048 + m ; MODE 3: bf16 head-major ((b*16+h)*2048+m)*64+d
template <int MODE>
__device__ __forceinline__ void gemm2_body(const u16* __restrict__ A,
                                           const u16* __restrict__ Bt,
                                           const float* __restrict__ bias,
                                           void* __restrict__ C, int N, int K) {
    __shared__ __align__(16) u16 As[128 * 32];
    __shared__ __align__(16) u16 Bs[128 * 32];
    int tid = threadIdx.x;
    int lane = tid & 63, w = tid >> 6;
    int ln = lane & 15, quad = lane >> 4;
    int m0 = blockIdx.x * 128, n0 = blockIdx.y * 128;
    int wm = (w >> 1) * 64, wn = (w & 1) * 64;
    float4v acc[4][4];
    float4v zero = {0.f, 0.f, 0.f, 0.f};
#pragma unroll
    for (int mi = 0; mi < 4; mi++)
#pragma unroll
        for (int ni = 0; ni < 4; ni++) acc[mi][ni] = zero;

    int r1 = tid >> 2, o1 = (tid & 3) * 8;
    const u16* ga1 = A + (size_t)(m0 + r1) * K + o1;
    const u16* gb1 = Bt + (size_t)(n0 + r1) * K + o1;
    u16* sa1 = &As[r1 * 32 + o1];
    u16* sb1 = &Bs[r1 * 32 + o1];
    size_t step2 = (size_t)64 * K;

    for (int k0 = 0; k0 < K; k0 += 32) {
        short8 va1 = *(const short8*)(ga1 + k0);
        short8 va2 = *(const short8*)(ga1 + step2 + k0);
        short8 vb1 = *(const short8*)(gb1 + k0);
        short8 vb2 = *(const short8*)(gb1 + step2 + k0);
        __syncthreads();
        *(short8*)sa1 = va1; *(short8*)(sa1 + 2048) = va2;
        *(short8*)sb1 = vb1; *(short8*)(sb1 + 2048) = vb2;
        __syncthreads();
        short8 af[4], bf[4];
#pragma unroll
        for (int mi = 0; mi < 4; mi++)
            af[mi] = *(const short8*)&As[(wm + mi * 16 + ln) * 32 + quad * 8];
#pragma unroll
        for (int ni = 0; ni < 4; ni++)
            bf[ni] = *(const short8*)&Bs[(wn + ni * 16 + ln) * 32 + quad * 8];
#pragma unroll
        for (int mi = 0; mi < 4; mi++)
#pragma unroll
            for (int ni = 0; ni < 4; ni++)
                acc[mi][ni] = MFMA16(af[mi], bf[ni], acc[mi][ni]);
    }

#pragma unroll
    for (int mi = 0; mi < 4; mi++) {
        int row0 = m0 + wm + mi * 16 + quad * 4;
#pragma unroll
        for (int ni = 0; ni < 4; ni++) {
            int col = n0 + wn + ni * 16 + ln;
            float bv = bias[col];
            if (MODE == 0) {
                u16* Cb = (u16*)C;
#pragma unroll
                for (int r = 0; r < 4; r++)
                    Cb[(size_t)(row0 + r) * N + col] = f2b(acc[mi][ni][r] + bv);
            } else if (MODE == 1) {
                float* Cf = (float*)C;
#pragma unroll
                for (int r = 0; r < 4; r++)
                    Cf[(size_t)(row0 + r) * N + col] = acc[mi][ni][r] + bv;
            } else if (MODE == 2) {
                u16* Cb = (u16*)C;
                int bb = row0 >> 11, s = row0 & 2047;
                ushort4 r4;
                r4.x = f2b(acc[mi][ni][0] + bv);
                r4.y = f2b(acc[mi][ni][1] + bv);
                r4.z = f2b(acc[mi][ni][2] + bv);
                r4.w = f2b(acc[mi][ni][3] + bv);
                *(ushort4*)(Cb + ((size_t)(bb * 1024 + col)) * 2048 + s) = r4;
            } else {
                u16* Cb = (u16*)C;
                int bb = row0 >> 11, s = row0 & 2047;
                int h = col >> 6, d = col & 63;
#pragma unroll
                for (int r = 0; r < 4; r++)
                    Cb[((size_t)(bb * 16 + h) * 2048 + s + r) * 64 + d] = f2b(acc[mi][ni][r] + bv);
            }
        }
    }
}

template <int MODE>
__global__ __launch_bounds__(256) void k_gemm2(const u16* __restrict__ A, const u16* __restrict__ Bt,
                                               const float* __restrict__ bias, void* __restrict__ C,
                                               int N, int K) {
    gemm2_body<MODE>(A, Bt, bias, C, N, K);
}

template <int MODE>
__global__ __launch_bounds__(256) void k_gemm2_dual(const u16* __restrict__ A,
                                                    const u16* __restrict__ Bt0, const u16* __restrict__ Bt1,
                                                    const float* __restrict__ b0, const float* __restrict__ b1,
                                                    void* __restrict__ C0, void* __restrict__ C1,
                                                    int N, int K) {
    if (blockIdx.z == 0) gemm2_body<MODE>(A, Bt0, b0, C0, N, K);
    else                 gemm2_body<MODE>(A, Bt1, b1, C1, N, K);
}

// Q/K/V projections in one launch (z: 0=Q head-major, 1=K head-major, 2=V transposed)
__global__ __launch_bounds__(256) void k_qkv(const u16* __restrict__ A,
                                             const u16* __restrict__ W0, const u16* __restrict__ W1,
                                             const u16* __restrict__ W2,
                                             const float* __restrict__ b0, const float* __restrict__ b1,
                                             const float* __restrict__ b2,
                                             u16* __restrict__ Q, u16* __restrict__ K, u16* __restrict__ VT) {
    if (blockIdx.z == 0)      gemm2_body<3>(A, W0, b0, Q, H, H);
    else if (blockIdx.z == 1) gemm2_body<3>(A, W1, b1, K, H, H);
    else                      gemm2_body<2>(A, W2, b2, VT, H, H);
}

// ---------------- both positional score tables, one launch ----------------
// z even: c2p[bh][q][p] (direct coalesced store); z odd: p2cT[bh][p][k] via LDS transpose
// (fixes the 8x write amplification of the old per-lane strided store).
__global__ __launch_bounds__(256) void k_pos_both(const u16* __restrict__ Qh, const u16* __restrict__ Kh,
                                                  const u16* __restrict__ pk, const u16* __restrict__ pq,
                                                  u16* __restrict__ c2p, u16* __restrict__ p2cT) {
    __shared__ __align__(16) u16 smem[2 * 128 * 72];   // As | Bs ; reused as Ts[128][136]
    u16* As = smem;
    u16* Bs = smem + 128 * 72;
    int tid = threadIdx.x;
    int lane = tid & 63, w = tid >> 6;
    int ln = lane & 15, quad = lane >> 4;
    int tr = blockIdx.z & 1, z = blockIdx.z >> 1, h = z & 15;
    int m0 = blockIdx.x * 128, n0 = blockIdx.y * 128;
    const u16* A = (tr ? Kh : Qh) + (size_t)z * S * HD;
    const u16* B = (tr ? pq : pk) + h * 64;
    int sr = tid >> 1, scb = (tid & 1) * 32;
    {
        const u16* ga = A + (size_t)(m0 + sr) * HD + scb;
        const u16* gb = B + (size_t)(n0 + sr) * H + scb;
#pragma unroll
        for (int j = 0; j < 4; j++) {
            *(short8*)&As[sr * 72 + scb + j * 8] = *(const short8*)(ga + j * 8);
            *(short8*)&Bs[sr * 72 + scb + j * 8] = *(const short8*)(gb + j * 8);
        }
    }
    __syncthreads();
    int wm = (w >> 1) * 64, wn = (w & 1) * 64;
    float4v acc[4][4];
    float4v zero = {0.f, 0.f, 0.f, 0.f};
#pragma unroll
    for (int mi = 0; mi < 4; mi++)
#pragma unroll
        for (int ni = 0; ni < 4; ni++) acc[mi][ni] = zero;
#pragma unroll
    for (int c = 0; c < 2; c++) {
        short8 af[4], bf[4];
#pragma unroll
        for (int mi = 0; mi < 4; mi++)
            af[mi] = *(const short8*)&As[(wm + mi * 16 + ln) * 72 + c * 32 + quad * 8];
#pragma unroll
        for (int ni = 0; ni < 4; ni++)
            bf[ni] = *(const short8*)&Bs[(wn + ni * 16 + ln) * 72 + c * 32 + quad * 8];
#pragma unroll
        for (int mi = 0; mi < 4; mi++)
#pragma unroll
            for (int ni = 0; ni < 4; ni++)
                acc[mi][ni] = MFMA16(af[mi], bf[ni], acc[mi][ni]);
    }
    if (!tr) {
        u16* Cp = c2p + (size_t)z * S * 512;
#pragma unroll
        for (int mi = 0; mi < 4; mi++) {
            int row0 = m0 + wm + mi * 16 + quad * 4;
#pragma unroll
            for (int ni = 0; ni < 4; ni++) {
                int col = n0 + wn + ni * 16 + ln;
#pragma unroll
                for (int r = 0; r < 4; r++)
                    Cp[(size_t)(row0 + r) * 512 + col] = f2b(acc[mi][ni][r] * SC);
            }
        }
    } else {
        // transpose through LDS, then coalesced row stores of p2cT[p][m]
        __syncthreads();   // all waves done reading As/Bs
        u16* Ts = smem;    // Ts[p_local][m_local] with stride 136
#pragma unroll
        for (int mi = 0; mi < 4; mi++) {
            int rl0 = wm + mi * 16 + quad * 4;
#pragma unroll
            for (int ni = 0; ni < 4; ni++) {
                int cl = wn + ni * 16 + ln;
#pragma unroll
                for (int r = 0; r < 4; r++)
                    Ts[cl * 136 + rl0 + r] = f2b(acc[mi][ni][r] * SC);
            }
        }
        __syncthreads();
        u16* Cp = p2cT + (size_t)z * 512 * S;
        int pr = tid >> 1, mb = (tid & 1) * 64;
        u16* dst = Cp + (size_t)(n0 + pr) * S + m0 + mb;
        const u16* src = Ts + pr * 136 + mb;
#pragma unroll
        for (int j = 0; j < 8; j++)
            *(short8*)(dst + j * 8) = *(const short8*)(src + j * 8);
    }
}

// ---------------- fused attention: K/V tiles staged in LDS (shared by 4 waves) ----------------
template <int SPLIT>
__global__ __launch_bounds__(256, 4) void k_attn(const u16* __restrict__ Qh,
                                                 const u16* __restrict__ Kh,
                                                 const u16* __restrict__ VT,
                                                 const u16* __restrict__ c2p,
                                                 const u16* __restrict__ p2cT,
                                                 const short* __restrict__ idxTab,
                                                 float* __restrict__ oP,
                                                 float* __restrict__ lP,
                                                 u16* __restrict__ ctx) {
    __shared__ short s_idx1[1024];
    __shared__ __align__(16) u16 p_lds[4][16][72];
    __shared__ __align__(16) u16 Ks[64][72];
    __shared__ __align__(16) u16 Vs[64][72];
    int tid = threadIdx.x;
    for (int i = tid; i < 1024; i += 256) s_idx1[i] = idxTab[i];
    int lane = tid & 63, w = tid >> 6;
    int ln = lane & 15, quad = lane >> 4;
    int bx = blockIdx.x;
    int half = (SPLIT == 2) ? (bx & 1) : 0;
    int q0 = (SPLIT == 2) ? (bx >> 1) * 64 : bx * 64;
    int bh = blockIdx.y;
    int b = bh >> 4, h = bh & 15;
    int qs = q0 + w * 16;

    const u16* qptr = Qh + ((size_t)bh * S + qs + ln) * HD + quad * 8;
    short8 aq0 = *(const short8*)(qptr);
    short8 aq1 = *(const short8*)(qptr + 32);

    float4v o[4];
    float4v zero = {0.f, 0.f, 0.f, 0.f};
#pragma unroll
    for (int f = 0; f < 4; f++) o[f] = zero;
    float lrw[4] = {0.f, 0.f, 0.f, 0.f};

    const u16* c2pB = c2p + (size_t)bh * S * 512;
    const u16* p2cB = p2cT + (size_t)bh * 512 * S;
    int qrow = qs + quad * 4;

    // staging map: thread -> (row sr 0..63, col block sc 0..48 step 16)
    int sr = tid >> 2, sc = (tid & 3) * 16;
    const u16* kstg = Kh + ((size_t)bh * S + sr) * HD + sc;              // + kk*HD per tile
    const u16* vstg = VT + (size_t)(b * 1024 + h * 64 + sr) * S + sc;    // + kk per tile

    const int NT = S / 64 / SPLIT;
    for (int t = 0; t < NT; t++) {
        int kk = (SPLIT == 2) ? (((t << 1) | half) << 6) : (t << 6);
        // ---- stage K,V tile (all waves cooperate) ----
        short8 kr0 = *(const short8*)(kstg + (size_t)kk * HD);
        short8 kr1 = *(const short8*)(kstg + (size_t)kk * HD + 8);
        short8 vr0 = *(const short8*)(vstg + kk);
        short8 vr1 = *(const short8*)(vstg + kk + 8);
        __syncthreads();
        *(short8*)&Ks[sr][sc] = kr0; *(short8*)&Ks[sr][sc + 8] = kr1;
        *(short8*)&Vs[sr][sc] = vr0; *(short8*)&Vs[sr][sc + 8] = vr1;
        __syncthreads();
        // ---- QK^T from LDS ----
        float4v sa[4];
#pragma unroll
        for (int f = 0; f < 4; f++) {
            short8 b0 = *(const short8*)&Ks[f * 16 + ln][quad * 8];
            short8 b1 = *(const short8*)&Ks[f * 16 + ln][32 + quad * 8];
            float4v tt = zero;
            tt = MFMA16(aq0, b0, tt);
            tt = MFMA16(aq1, b1, tt);
            sa[f] = tt;
        }
        // ---- positional bias + exp2 (fixed max 0) ----
        int rel0 = q0 - kk;
        if (rel0 >= 569 || rel0 <= -633) {
            int idx = rel0 > 0 ? 511 : 0;
            float cvr[4];
#pragma unroll
            for (int r = 0; r < 4; r++)
                cvr[r] = b2f(c2pB[(size_t)(qrow + r) * 512 + idx]);
            const u16* prow = p2cB + (size_t)idx * S + kk;
#pragma unroll
            for (int f = 0; f < 4; f++) {
                float pv = b2f(prow[f * 16 + ln]);
#pragma unroll
                for (int r = 0; r < 4; r++) {
                    float p = exp2f(sa[f][r] * SC + cvr[r] + pv);
                    lrw[r] += p;
                    p_lds[w][quad * 4 + r][f * 16 + ln] = f2b(p);
                }
            }
        } else {
#pragma unroll
            for (int f = 0; f < 4; f++) {
                int ki = kk + f * 16 + ln;
                int relb = qrow - ki;
#pragma unroll
                for (int r = 0; r < 4; r++) {
                    int rel = relb + r;
                    rel = rel < -512 ? -512 : (rel > 511 ? 511 : rel);
                    int idx = (int)s_idx1[rel + 512];
                    float cv = b2f(c2pB[(size_t)(qrow + r) * 512 + idx]);
                    float pv = b2f(p2cB[(size_t)idx * S + ki]);
                    float p = exp2f(sa[f][r] * SC + cv + pv);
                    lrw[r] += p;
                    p_lds[w][quad * 4 + r][f * 16 + ln] = f2b(p);
                }
            }
        }
        // ---- PV from LDS (own-wave P slice, no extra barrier) ----
        short8 ap0 = *(const short8*)&p_lds[w][ln][quad * 8];
        short8 ap1 = *(const short8*)&p_lds[w][ln][32 + quad * 8];
#pragma unroll
        for (int f = 0; f < 4; f++) {
            short8 v0 = *(const short8*)&Vs[f * 16 + ln][quad * 8];
            short8 v1 = *(const short8*)&Vs[f * 16 + ln][32 + quad * 8];
            o[f] = MFMA16(ap0, v0, o[f]);
            o[f] = MFMA16(ap1, v1, o[f]);
        }
    }
    // ---- single end-of-loop l reduction (within 16-lane quad) ----
#pragma unroll
    for (int r = 0; r < 4; r++) {
        lrw[r] += __shfl_xor(lrw[r], 1, 16);
        lrw[r] += __shfl_xor(lrw[r], 2, 16);
        lrw[r] += __shfl_xor(lrw[r], 4, 16);
        lrw[r] += __shfl_xor(lrw[r], 8, 16);
    }
    if (SPLIT == 1) {
        float inv_l[4];
#pragma unroll
        for (int r = 0; r < 4; r++) inv_l[r] = 1.f / lrw[r];
#pragma unroll
        for (int f = 0; f < 4; f++)
#pragma unroll
            for (int r = 0; r < 4; r++) {
                int qi = qs + quad * 4 + r;
                ctx[(size_t)(b * S + qi) * H + h * 64 + f * 16 + ln] = f2b(o[f][r] * inv_l[r]);
            }
    } else {
        float* oH = oP + (size_t)half * SP_OHALF;
#pragma unroll
        for (int f = 0; f < 4; f++)
#pragma unroll
            for (int r = 0; r < 4; r++) {
                int qi = qs + quad * 4 + r;
                oH[((size_t)bh * S + qi) * 64 + f * 16 + ln] = o[f][r];
            }
        if (ln == 0) {
            float* lH = lP + (size_t)half * SP_LHALF;
#pragma unroll
            for (int r = 0; r < 4; r++)
                lH[(size_t)bh * S + qs + quad * 4 + r] = lrw[r];
        }
    }
}

// ---------------- merge split-K partials -> ctx bf16 ----------------
__global__ __launch_bounds__(256) void k_merge(const float* __restrict__ oP,
                                               const float* __restrict__ lP,
                                               u16* __restrict__ ctx) {
    int t = blockIdx.x * 256 + threadIdx.x;
    int d4 = (t & 15) * 4;
    int h  = (t >> 4) & 15;
    int qq = (t >> 8) & 2047;
    int b  = t >> 19;
    int bh = b * 16 + h;
    size_t base = ((size_t)bh * S + qq) * 64 + d4;
    float4 o0 = *(const float4*)(oP + base);
    float4 o1 = *(const float4*)(oP + SP_OHALF + base);
    float l0 = lP[(size_t)bh * S + qq];
    float l1 = lP[SP_LHALF + (size_t)bh * S + qq];
    float inv = 1.f / (l0 + l1);
    ushort4 r4;
    r4.x = f2b((o0.x + o1.x) * inv);
    r4.y = f2b((o0.y + o1.y) * inv);
    r4.z = f2b((o0.z + o1.z) * inv);
    r4.w = f2b((o0.w + o1.w) * inv);
    *(ushort4*)(ctx + (((size_t)(b * S + qq)) * 16 + h) * 64 + d4) = r4;
}

// ---------------- launch ----------------
extern "C" void kernel_launch(void* const* d_in, const int* in_sizes, int n_in,
                              void* d_out, int out_size, void* d_ws, size_t ws_size,
                              hipStream_t stream) {
    const float* hs  = (const float*)d_in[0];
    const float* Wq  = (const float*)d_in[1];
    const float* bq  = (const float*)d_in[2];
    const float* Wk  = (const float*)d_in[3];
    const float* bk  = (const float*)d_in[4];
    const float* Wv  = (const float*)d_in[5];
    const float* bv  = (const float*)d_in[6];
    const float* Wo  = (const float*)d_in[7];
    const float* bo  = (const float*)d_in[8];
    const float* Wpk = (const float*)d_in[9];
    const float* bpk = (const float*)d_in[10];
    const float* Wpq = (const float*)d_in[11];
    const float* bpq = (const float*)d_in[12];
    const float* rel = (const float*)d_in[13];
    const float* lng = (const float*)d_in[14];
    const float* lnb = (const float*)d_in[15];

    char* ws = (char*)d_ws;
    u16* re_b   = (u16*)(ws + OFF_REB);
    u16* hs_b   = (u16*)(ws + OFF_HSB);
    u16* wt0    = (u16*)(ws + OFF_WT);
    u16* wt1    = (u16*)(ws + OFF_WT + 2097152ull);
    u16* wt2    = (u16*)(ws + OFF_WT + 2ull * 2097152ull);
    u16* wt3    = (u16*)(ws + OFF_WT + 3ull * 2097152ull);
    u16* wt4    = (u16*)(ws + OFF_WT + 4ull * 2097152ull);
    u16* wt5    = (u16*)(ws + OFF_WT + 5ull * 2097152ull);
    u16* Q_b    = (u16*)(ws + OFF_QB);
    u16* K_b    = (u16*)(ws + OFF_KB);
    u16* VT_b   = (u16*)(ws + OFF_VT);
    u16* posk_b = (u16*)(ws + OFF_PKB);
    u16* posq_b = (u16*)(ws + OFF_PQB);
    u16* c2p_b  = (u16*)(ws + OFF_C2P);
    u16* p2cT_b = (u16*)(ws + OFF_P2CT);
    u16* ctx_b  = (u16*)(ws + OFF_CTX);
    short* idx_t = (short*)(ws + OFF_IDX);
    float* oP   = (float*)(ws + OFF_SP);
    float* lP   = (float*)(ws + SP_LBASE);

    dim3 blk(256);
    k_build_idx<<<dim3(4), blk, 0, stream>>>(idx_t);
    k_ln<<<dim3(512), blk, 0, stream>>>(rel, lng, lnb, re_b);
    k_cast<<<dim3(4096), blk, 0, stream>>>(hs, hs_b);
    k_wt6<<<dim3(16, 16, 6), blk, 0, stream>>>(Wq, Wk, Wv, Wo, Wpk, Wpq,
                                               wt0, wt1, wt2, wt3, wt4, wt5);

    // projections
    k_qkv<<<dim3(32, 8, 3), blk, 0, stream>>>(hs_b, wt0, wt1, wt2, bq, bk, bv, Q_b, K_b, VT_b);
    k_gemm2_dual<0><<<dim3(4, 8, 2), blk, 0, stream>>>(re_b, wt4, wt5, bpk, bpq, posk_b, posq_b, H, H);

    // positional score tables (scale incl. log2e folded in)
    k_pos_both<<<dim3(16, 4, 64), blk, 0, stream>>>(Q_b, K_b, posk_b, posq_b, c2p_b, p2cT_b);

    // fused attention (split-K x2 interleaved when workspace allows)
    if (ws_size >= WS_NEED_SPLIT) {
        k_attn<2><<<dim3(64, 32), blk, 0, stream>>>(Q_b, K_b, VT_b, c2p_b, p2cT_b, idx_t, oP, lP, ctx_b);
        k_merge<<<dim3(4096), blk, 0, stream>>>(oP, lP, ctx_b);
    } else {
        k_attn<1><<<dim3(32, 32), blk, 0, stream>>>(Q_b, K_b, VT_b, c2p_b, p2cT_b, idx_t, oP, lP, ctx_b);
    }

    // output projection (fp32 out)
    k_gemm2<1><<<dim3(32, 8), blk, 0, stream>>>(ctx_b, wt3, bo, d_out, H, H);
}